// Round 5
// baseline (414.264 us; speedup 1.0000x reference)
//
#include <hip/hip_runtime.h>
#include <stdint.h>

#define DMODEL 1024
#define NHEADS 16
#define DK     64
#define BATCH  4
#define SEQ    2048
#define MROWS  (BATCH*SEQ)   // 8192

typedef __bf16   bf16x8 __attribute__((ext_vector_type(8)));
typedef float    f32x4  __attribute__((ext_vector_type(4)));
typedef _Float16 f16x4  __attribute__((ext_vector_type(4)));
typedef _Float16 f16x2  __attribute__((ext_vector_type(2)));

#if defined(__has_builtin)
#if __has_builtin(__builtin_amdgcn_exp2f)
#define EXP2F(x) __builtin_amdgcn_exp2f(x)
#endif
#endif
#ifndef EXP2F
#define EXP2F(x) exp2f(x)
#endif

__device__ __forceinline__ unsigned short f2bf(float f) {
    unsigned int u = __builtin_bit_cast(unsigned int, f);
    u += 0x7fffu + ((u >> 16) & 1u);   // round-to-nearest-even
    return (unsigned short)(u >> 16);
}

// pack two f32 -> two bf16 (round-to-nearest) in one v_perm
__device__ __forceinline__ unsigned int pack_bf16(float a, float b) {
    unsigned int ua = __builtin_bit_cast(unsigned int, a) + 0x8000u;
    unsigned int ub = __builtin_bit_cast(unsigned int, b) + 0x8000u;
    return __builtin_amdgcn_perm(ub, ua, 0x07060302u);  // lo16=a.hi16, hi16=b.hi16
}
// pack two f32 -> two fp16 (RTZ), single instruction
__device__ __forceinline__ unsigned int pack_f16(float a, float b) {
    return __builtin_bit_cast(unsigned int, __builtin_amdgcn_cvt_pkrtz(a, b));
}

// async global->LDS, 16 B per lane, LDS dest = uniform base + lane*16
#define GLDS(gp, lp) __builtin_amdgcn_global_load_lds( \
    (const __attribute__((address_space(1))) unsigned int*)(gp), \
    (__attribute__((address_space(3))) unsigned int*)(lp), 16, 0, 0)

// ---------------- fp32 -> bf16 cast, 4 elems/thread ----------------
__global__ void cvt_kernel(const float* __restrict__ src,
                           unsigned short* __restrict__ dst, int n4) {
    int i = blockIdx.x * blockDim.x + threadIdx.x;
    if (i >= n4) return;
    const float4 v = reinterpret_cast<const float4*>(src)[i];
    uint2 o;
    o.x = pack_bf16(v.x, v.y);
    o.y = pack_bf16(v.z, v.w);
    reinterpret_cast<uint2*>(dst)[i] = o;
}

// 4 weight matrices (1024x1024 each) in one launch; blockIdx.y selects
__global__ void cvtw_kernel(const float* __restrict__ w0, const float* __restrict__ w1,
                            const float* __restrict__ w2, const float* __restrict__ w3,
                            unsigned short* __restrict__ d0, unsigned short* __restrict__ d1,
                            unsigned short* __restrict__ d2, unsigned short* __restrict__ d3) {
    const float* s; unsigned short* d;
    switch (blockIdx.y) {
        case 0:  s = w0; d = d0; break;
        case 1:  s = w1; d = d1; break;
        case 2:  s = w2; d = d2; break;
        default: s = w3; d = d3; break;
    }
    const int i = blockIdx.x * blockDim.x + threadIdx.x;
    const float4 v = reinterpret_cast<const float4*>(s)[i];
    uint2 o;
    o.x = pack_bf16(v.x, v.y);
    o.y = pack_bf16(v.z, v.w);
    reinterpret_cast<uint2*>(d)[i] = o;
}

// mask[B,L] int32 -> float bias (0 or -1e30)
__global__ void maskbias_kernel(const int* __restrict__ m, float* __restrict__ o, int n) {
    const int i = blockIdx.x * blockDim.x + threadIdx.x;
    if (i < n) o[i] = m[i] ? 0.f : -1e30f;
}

// ---------------- 128x128-tile GEMM, BK=64, LDS staged ----------------
// C[M,N] = A[M,1024] * W[N,1024]^T + bias
// MODE 0: fused QKV. blockIdx.x: 0..23 -> which = x>>3 (0=Q,1=K,2=V), ntile = x&7
//   Q (scaled 0.125*log2e), K: C^T orientation, bf16 scatter -> [BH, L, 64]
//   V: C orientation, fp16 scatter -> blocked [BH, kblk, dv, 64]
// MODE 1: C^T orientation, fp32 row-major out [M, 1024]
template<int MODE>
__global__ __launch_bounds__(256, 3) void gemm128(
        const unsigned short* __restrict__ A,
        const unsigned short* __restrict__ W0,
        const unsigned short* __restrict__ W1,
        const unsigned short* __restrict__ W2,
        const float* __restrict__ b0,
        const float* __restrict__ b1,
        const float* __restrict__ b2,
        void* __restrict__ o0, void* __restrict__ o1, void* __restrict__ o2) {
    __shared__ unsigned short As[128 * 64];   // 16 KB, rows of 64 bf16, chunk-swizzled
    __shared__ unsigned short Bs[128 * 64];   // 16 KB
    const int lane = threadIdx.x & 63;
    const int wave = threadIdx.x >> 6;
    const int quad = lane >> 4;
    const int r15  = lane & 15;
    const int wr = wave >> 1, wc = wave & 1;
    const int m0 = blockIdx.y * 128;

    int which, ncol0;
    const unsigned short* W;
    const float* bias;
    if (MODE == 0) {
        which = blockIdx.x >> 3;
        ncol0 = (blockIdx.x & 7) * 128;
        W    = which == 0 ? W0 : (which == 1 ? W1 : W2);
        bias = which == 0 ? b0 : (which == 1 ? b1 : b2);
    } else {
        which = 0; ncol0 = blockIdx.x * 128; W = W0; bias = b0;
    }

    // staging: lane covers (row = seg*8 + lane/8, chunk = lane&7),
    // global chunk swizzled by row&7 so LDS stays DMA-contiguous yet reads conflict-free
    const int srow = lane >> 3;
    const int scg  = (lane & 7) ^ srow;
    const unsigned short* Ag[4];
    const unsigned short* Wg[4];
    #pragma unroll
    for (int j = 0; j < 4; ++j) {
        const int row = (wave * 4 + j) * 8 + srow;
        Ag[j] = A + (m0 + row) * DMODEL + scg * 8;
        Wg[j] = W + (ncol0 + row) * DMODEL + scg * 8;
    }

    const bool ct = (MODE == 1) || (MODE == 0 && /*which set below? no—*/ false) || false;
    // (orientation decided per 'which' at MFMA time; V keeps C, Q/K/out use C^T)
    const bool swap_ops = (MODE == 1) || (MODE == 0 ? true : false);  // overridden for V below
    (void)ct; (void)swap_ops;

    f32x4 acc[4][4] = {};
    const bool use_ct = (MODE == 1) || (which < 2);   // C^T for Q, K, out; C for V
    for (int kk = 0; kk < DMODEL; kk += 64) {
        __syncthreads();
        #pragma unroll
        for (int j = 0; j < 4; ++j) {
            GLDS(Ag[j] + kk, &As[(wave * 4 + j) * 512]);
            GLDS(Wg[j] + kk, &Bs[(wave * 4 + j) * 512]);
        }
        __syncthreads();
        #pragma unroll
        for (int u = 0; u < 2; ++u) {
            bf16x8 af[4], bfx[4];
            const int cs = ((u * 4 + quad) ^ (r15 & 7)) * 8;
            #pragma unroll
            for (int t = 0; t < 4; ++t) {
                af[t]  = *(const bf16x8*)&As[(wr * 64 + t * 16 + r15) * 64 + cs];
                bfx[t] = *(const bf16x8*)&Bs[(wc * 64 + t * 16 + r15) * 64 + cs];
            }
            if (use_ct) {
                #pragma unroll
                for (int mt = 0; mt < 4; ++mt)
                    #pragma unroll
                    for (int nt = 0; nt < 4; ++nt)
                        acc[mt][nt] = __builtin_amdgcn_mfma_f32_16x16x32_bf16(
                            bfx[nt], af[mt], acc[mt][nt], 0, 0, 0);
            } else {
                #pragma unroll
                for (int mt = 0; mt < 4; ++mt)
                    #pragma unroll
                    for (int nt = 0; nt < 4; ++nt)
                        acc[mt][nt] = __builtin_amdgcn_mfma_f32_16x16x32_bf16(
                            af[mt], bfx[nt], acc[mt][nt], 0, 0, 0);
            }
        }
    }

    // epilogue
    #pragma unroll
    for (int mt = 0; mt < 4; ++mt) {
        #pragma unroll
        for (int nt = 0; nt < 4; ++nt) {
            if (MODE == 1) {
                // C^T: row = r15-based, 4 consecutive cols per lane -> float4 store
                const int row  = m0 + wr * 64 + mt * 16 + r15;
                const int col0 = ncol0 + wc * 64 + nt * 16 + quad * 4;
                const float4 b4 = *(const float4*)&bias[col0];
                float4 v;
                v.x = acc[mt][nt][0] + b4.x;
                v.y = acc[mt][nt][1] + b4.y;
                v.z = acc[mt][nt][2] + b4.z;
                v.w = acc[mt][nt][3] + b4.w;
                *(float4*)&((float*)o0)[(size_t)row * DMODEL + col0] = v;
            } else if (which < 2) {
                // C^T: 4 consecutive d per lane -> uint2 bf16 store to [BH, L, 64]
                const int row  = m0 + wr * 64 + mt * 16 + r15;
                const int col0 = ncol0 + wc * 64 + nt * 16 + quad * 4;
                const float4 b4 = *(const float4*)&bias[col0];
                float v0 = acc[mt][nt][0] + b4.x;
                float v1 = acc[mt][nt][1] + b4.y;
                float v2 = acc[mt][nt][2] + b4.z;
                float v3 = acc[mt][nt][3] + b4.w;
                if (which == 0) {
                    const float sc = 0.18033688011112042f;  // 0.125*log2(e)
                    v0 *= sc; v1 *= sc; v2 *= sc; v3 *= sc;
                }
                const int b = row >> 11, l = row & (SEQ - 1);
                const int h = col0 >> 6, d0 = col0 & (DK - 1);
                const int bh = b * NHEADS + h;
                unsigned short* ow = (unsigned short*)(which == 0 ? o0 : o1);
                uint2 pw;
                pw.x = pack_bf16(v0, v1);
                pw.y = pack_bf16(v2, v3);
                *(uint2*)&ow[((size_t)bh * SEQ + l) * DK + d0] = pw;
            } else {
                // V, C orientation: 4 consecutive l per lane -> uint2 fp16 store
                // blocked [BH, l>>6, dv, l&63]
                const int row0 = m0 + wr * 64 + mt * 16 + quad * 4;   // l base
                const int col  = ncol0 + wc * 64 + nt * 16 + r15;
                const float bb = bias[col];
                const float v0 = acc[mt][nt][0] + bb;
                const float v1 = acc[mt][nt][1] + bb;
                const float v2 = acc[mt][nt][2] + bb;
                const float v3 = acc[mt][nt][3] + bb;
                const int b = row0 >> 11, l0 = row0 & (SEQ - 1);
                const int h = col >> 6, d = col & (DK - 1);
                const int bh = b * NHEADS + h;
                uint2 pw;
                pw.x = pack_f16(v0, v1);
                pw.y = pack_f16(v2, v3);
                unsigned short* ow = (unsigned short*)o2;
                *(uint2*)&ow[(size_t)bh * (SEQ * DK) + (l0 >> 6) * (DK * 64) + d * 64 + (l0 & 63)] = pw;
            }
        }
    }
}

// ---------------- Flash attention, LDS-staged K/V, register P ----------------
// Q (pre-scaled by 0.125*log2e), K: [BH, L, 64] bf16; Vm: blocked fp16 [BH, kblk, dv, 64];
// mbf: [B,L] float bias (0 / -1e30). Out: bf16 [B, L, DMODEL], col = h*64+dv.
// S^T accumulator C-layout (key=quad*4+r, query=r15) doubles as the B-fragment of
// mfma_f32_16x16x16f16 (k=quad*4+j, n=lane&15) -> PV computed as O^T = V^T * P^T
// with zero LDS round-trip for P.
__global__ __launch_bounds__(256, 4) void flash_attn(
        const unsigned short* __restrict__ Q,
        const unsigned short* __restrict__ Km,
        const unsigned short* __restrict__ Vm,
        const float* __restrict__ mbf,
        unsigned short* __restrict__ Oa) {
    __shared__ unsigned short Ks[64 * 64];        // 8 KB  [key][dk] swizzled
    __shared__ unsigned short Vs[64 * 64];        // 8 KB  fp16 [dv][key] swizzled
    const int lane = threadIdx.x & 63;
    const int wave = threadIdx.x >> 6;
    const int quad = lane >> 4;
    const int r15  = lane & 15;

    // XCD-aware remap: each XCD walks one head's 16 q-tiles before moving on
    const int id   = (blockIdx.y << 4) | blockIdx.x;   // gridDim.x == 16
    const int xcd  = id & 7;
    const int slot = id >> 3;                          // 0..127
    const int bh   = xcd + ((slot >> 4) << 3);         // 0..63
    const int qt   = slot & 15;
    const int b = bh >> 4, h = bh & (NHEADS - 1);
    const int q0 = qt * 128 + wave * 32;

    const unsigned short* Qb = Q  + (size_t)bh * SEQ * DK;
    const unsigned short* Kb = Km + (size_t)bh * SEQ * DK;
    const unsigned short* Vb = Vm + (size_t)bh * SEQ * DK;
    const float* mb = mbf + b * SEQ;

    const int srow = lane >> 3;
    const int soff = (srow * 64) + (((lane & 7) ^ srow) * 8);

    // Q fragments (B operand of S^T MFMA): 2 q-frags x 2 k-halves
    bf16x8 bq[2][2];
    #pragma unroll
    for (int qf = 0; qf < 2; ++qf)
        #pragma unroll
        for (int u = 0; u < 2; ++u)
            bq[qf][u] = *(const bf16x8*)(Qb + (q0 + qf * 16 + r15) * DK + u * 32 + quad * 8);

    float l_part[2] = {0.f, 0.f};
    f32x4 oacc[2][4] = {};

    for (int kb = 0; kb < SEQ; kb += 64) {
        __syncthreads();
        const unsigned short* Kg = Kb + kb * 64;   // 64 rows x 128 B, contiguous
        const unsigned short* Vg = Vb + kb * 64;   // blocked tile, contiguous
        #pragma unroll
        for (int j = 0; j < 2; ++j) {
            const int wseg = wave * 2 + j;
            GLDS(Kg + wseg * 512 + soff, &Ks[wseg * 512]);
            GLDS(Vg + wseg * 512 + soff, &Vs[wseg * 512]);
        }
        __syncthreads();

        f16x4 pfrag[4][2];
        #pragma unroll
        for (int t = 0; t < 4; ++t) {
            const bf16x8 ak0 = *(const bf16x8*)&Ks[(t * 16 + r15) * 64 + ((quad ^ (r15 & 7)) * 8)];
            const bf16x8 ak1 = *(const bf16x8*)&Ks[(t * 16 + r15) * 64 + (((4 + quad) ^ (r15 & 7)) * 8)];
            const float4 m4 = *(const float4*)(mb + kb + t * 16 + quad * 4);
            #pragma unroll
            for (int qf = 0; qf < 2; ++qf) {
                f32x4 z = {};
                z = __builtin_amdgcn_mfma_f32_16x16x32_bf16(ak0, bq[qf][0], z, 0, 0, 0);
                z = __builtin_amdgcn_mfma_f32_16x16x32_bf16(ak1, bq[qf][1], z, 0, 0, 0);
                // z = S^T (log2 domain): lane holds (key=t*16+quad*4+r, query=r15)
                const float p0 = EXP2F(z[0] + m4.x);
                const float p1 = EXP2F(z[1] + m4.y);
                const float p2 = EXP2F(z[2] + m4.z);
                const float p3 = EXP2F(z[3] + m4.w);
                l_part[qf] += (p0 + p1) + (p2 + p3);
                uint2 pw;
                pw.x = pack_f16(p0, p1);
                pw.y = pack_f16(p2, p3);
                pfrag[t][qf] = __builtin_bit_cast(f16x4, pw);
            }
        }

        // PV: O^T[dv][q] += V^T[dv][k] * P^T[k][q], 16x16x16 fp16 MFMA
        #pragma unroll
        for (int nt = 0; nt < 4; ++nt) {
            #pragma unroll
            for (int t = 0; t < 4; ++t) {
                // V^T A-frag: m=dv=nt*16+r15, k=key=t*16+quad*4.. (+3), swizzled chunk
                const int chunk = (2 * t + (quad >> 1)) ^ (r15 & 7);
                const f16x4 vf = *(const f16x4*)&Vs[(nt * 16 + r15) * 64 + chunk * 8 + (quad & 1) * 4];
                #pragma unroll
                for (int qf = 0; qf < 2; ++qf)
                    oacc[qf][nt] = __builtin_amdgcn_mfma_f32_16x16x16f16(
                        vf, pfrag[t][qf], oacc[qf][nt], 0, 0, 0);
            }
        }
    }

    #pragma unroll
    for (int qf = 0; qf < 2; ++qf) {
        float l = l_part[qf];
        l += __shfl_xor(l, 16);
        l += __shfl_xor(l, 32);                  // l for query r15 — already per-lane!
        const float rl = __builtin_amdgcn_rcpf(l);
        const int row = q0 + qf * 16 + r15;      // query
        #pragma unroll
        for (int nt = 0; nt < 4; ++nt) {
            // O^T C-layout: lane holds dv = nt*16 + quad*4 + r, query = r15
            const int col0 = h * DK + nt * 16 + quad * 4;
            uint2 pw;
            pw.x = pack_bf16(oacc[qf][nt][0] * rl, oacc[qf][nt][1] * rl);
            pw.y = pack_bf16(oacc[qf][nt][2] * rl, oacc[qf][nt][3] * rl);
            *(uint2*)&Oa[((size_t)b * SEQ + row) * DMODEL + col0] = pw;
        }
    }
}

extern "C" void kernel_launch(void* const* d_in, const int* in_sizes, int n_in,
                              void* d_out, int out_size, void* d_ws, size_t ws_size,
                              hipStream_t stream) {
    (void)in_sizes; (void)n_in; (void)out_size; (void)ws_size;
    const float* x  = (const float*)d_in[0];
    const int* mask = (const int*)d_in[1];
    const float* Wq = (const float*)d_in[2];
    const float* bq = (const float*)d_in[3];
    const float* Wk = (const float*)d_in[4];
    const float* bk = (const float*)d_in[5];
    const float* Wv = (const float*)d_in[6];
    const float* bv = (const float*)d_in[7];
    const float* Wo = (const float*)d_in[8];
    const float* bo = (const float*)d_in[9];
    float* out = (float*)d_out;

    char* ws = (char*)d_ws;
    unsigned short* xb  = (unsigned short*)(ws);                                   // 8192x1024 bf16
    unsigned short* wqb = (unsigned short*)(ws + 16777216);                        // 1024x1024 bf16
    unsigned short* wkb = (unsigned short*)(ws + 16777216 + 1 * 2097152);
    unsigned short* wvb = (unsigned short*)(ws + 16777216 + 2 * 2097152);
    unsigned short* wob = (unsigned short*)(ws + 16777216 + 3 * 2097152);
    unsigned short* qb  = (unsigned short*)(ws + 16777216 + 4 * 2097152);          // [BH,L,64]
    unsigned short* kb  = qb  + (size_t)MROWS * DMODEL;                            // [BH,L,64]
    unsigned short* vtb = kb  + (size_t)MROWS * DMODEL;                            // blocked V fp16
    unsigned short* ab  = vtb + (size_t)MROWS * DMODEL;                            // [B,L,DMODEL]
    float*          mbf = (float*)(ab + (size_t)MROWS * DMODEL);                   // [B,L]

    cvt_kernel<<<dim3(MROWS * DMODEL / 4 / 256), 256, 0, stream>>>(x, xb, MROWS * DMODEL / 4);
    cvtw_kernel<<<dim3(DMODEL * DMODEL / 4 / 256, 4), 256, 0, stream>>>(
        Wq, Wk, Wv, Wo, wqb, wkb, wvb, wob);
    maskbias_kernel<<<dim3(BATCH * SEQ / 256), 256, 0, stream>>>(mask, mbf, BATCH * SEQ);

    // fused QKV: grid.x = 3 weights x 8 n-tiles
    gemm128<0><<<dim3(24, MROWS / 128), 256, 0, stream>>>(
        xb, wqb, wkb, wvb, bq, bk, bv, qb, kb, vtb);

    flash_attn<<<dim3(16, BATCH * NHEADS), 256, 0, stream>>>(qb, kb, vtb, mbf, ab);

    gemm128<1><<<dim3(8, MROWS / 128), 256, 0, stream>>>(
        ab, wob, nullptr, nullptr, bo, nullptr, nullptr, out, nullptr, nullptr);
}

// Round 6
// 404.415 us; speedup vs baseline: 1.0244x; 1.0244x over previous
//
#include <hip/hip_runtime.h>
#include <stdint.h>

#define DMODEL 1024
#define NHEADS 16
#define DK     64
#define BATCH  4
#define SEQ    2048
#define MROWS  (BATCH*SEQ)   // 8192

typedef __bf16   bf16x8 __attribute__((ext_vector_type(8)));
typedef float    f32x4  __attribute__((ext_vector_type(4)));
typedef _Float16 f16x4  __attribute__((ext_vector_type(4)));

#if defined(__has_builtin)
#if __has_builtin(__builtin_amdgcn_exp2f)
#define EXP2F(x) __builtin_amdgcn_exp2f(x)
#endif
#endif
#ifndef EXP2F
#define EXP2F(x) exp2f(x)
#endif

__device__ __forceinline__ unsigned short f2bf(float f) {
    unsigned int u = __builtin_bit_cast(unsigned int, f);
    u += 0x7fffu + ((u >> 16) & 1u);   // round-to-nearest-even
    return (unsigned short)(u >> 16);
}

// pack two f32 -> two bf16 (round-to-nearest) in one v_perm
__device__ __forceinline__ unsigned int pack_bf16(float a, float b) {
    unsigned int ua = __builtin_bit_cast(unsigned int, a) + 0x8000u;
    unsigned int ub = __builtin_bit_cast(unsigned int, b) + 0x8000u;
    return __builtin_amdgcn_perm(ub, ua, 0x07060302u);  // lo16=a.hi16, hi16=b.hi16
}
// pack two f32 -> two fp16 (RTZ), single instruction
__device__ __forceinline__ unsigned int pack_f16(float a, float b) {
    return __builtin_bit_cast(unsigned int, __builtin_amdgcn_cvt_pkrtz(a, b));
}

// async global->LDS, 16 B per lane, LDS dest = uniform base + lane*16
#define GLDS(gp, lp) __builtin_amdgcn_global_load_lds( \
    (const __attribute__((address_space(1))) unsigned int*)(gp), \
    (__attribute__((address_space(3))) unsigned int*)(lp), 16, 0, 0)

// ---------------- fp32 -> bf16 cast, 4 elems/thread ----------------
__global__ void cvt_kernel(const float* __restrict__ src,
                           unsigned short* __restrict__ dst, int n4) {
    int i = blockIdx.x * blockDim.x + threadIdx.x;
    if (i >= n4) return;
    const float4 v = reinterpret_cast<const float4*>(src)[i];
    uint2 o;
    o.x = pack_bf16(v.x, v.y);
    o.y = pack_bf16(v.z, v.w);
    reinterpret_cast<uint2*>(dst)[i] = o;
}

// 4 weight matrices (1024x1024 each) in one launch; blockIdx.y selects
__global__ void cvtw_kernel(const float* __restrict__ w0, const float* __restrict__ w1,
                            const float* __restrict__ w2, const float* __restrict__ w3,
                            unsigned short* __restrict__ d0, unsigned short* __restrict__ d1,
                            unsigned short* __restrict__ d2, unsigned short* __restrict__ d3) {
    const float* s; unsigned short* d;
    switch (blockIdx.y) {
        case 0:  s = w0; d = d0; break;
        case 1:  s = w1; d = d1; break;
        case 2:  s = w2; d = d2; break;
        default: s = w3; d = d3; break;
    }
    const int i = blockIdx.x * blockDim.x + threadIdx.x;
    const float4 v = reinterpret_cast<const float4*>(s)[i];
    uint2 o;
    o.x = pack_bf16(v.x, v.y);
    o.y = pack_bf16(v.z, v.w);
    reinterpret_cast<uint2*>(d)[i] = o;
}

// mask[B,L] int32 -> float bias (0 or -1e30)
__global__ void maskbias_kernel(const int* __restrict__ m, float* __restrict__ o, int n) {
    const int i = blockIdx.x * blockDim.x + threadIdx.x;
    if (i < n) o[i] = m[i] ? 0.f : -1e30f;
}

// ---------------- 128x128-tile GEMM, BK=64, LDS staged ----------------
// C[M,N] = A[M,1024] * W[N,1024]^T + bias
// All epilogue stores keep consecutive lanes -> consecutive addresses (32/64 B
// runs) — scattered-lane stores defeat the TCC write coalescer (R5: 12.6x
// HBM write amplification).
// MODE 0: fused QKV. blockIdx.x: 0..23 -> which = x>>3 (0=Q,1=K,2=V), ntile = x&7
//   Q (scaled 0.125*log2e), K: C orientation (lanes=d), bf16 -> [BH, L, 64]
//   V: C^T orientation (lanes=l), fp16 -> blocked [BH, l>>6, dv, l&63]
// MODE 1: C orientation (lanes=cols), fp32 row-major out [M, 1024]
template<int MODE>
__global__ __launch_bounds__(256, 3) void gemm128(
        const unsigned short* __restrict__ A,
        const unsigned short* __restrict__ W0,
        const unsigned short* __restrict__ W1,
        const unsigned short* __restrict__ W2,
        const float* __restrict__ b0,
        const float* __restrict__ b1,
        const float* __restrict__ b2,
        void* __restrict__ o0, void* __restrict__ o1, void* __restrict__ o2) {
    __shared__ unsigned short As[128 * 64];   // 16 KB, rows of 64 bf16, chunk-swizzled
    __shared__ unsigned short Bs[128 * 64];   // 16 KB
    const int lane = threadIdx.x & 63;
    const int wave = threadIdx.x >> 6;
    const int quad = lane >> 4;
    const int r15  = lane & 15;
    const int wr = wave >> 1, wc = wave & 1;
    const int m0 = blockIdx.y * 128;

    int which, ncol0;
    const unsigned short* W;
    const float* bias;
    if (MODE == 0) {
        which = blockIdx.x >> 3;
        ncol0 = (blockIdx.x & 7) * 128;
        W    = which == 0 ? W0 : (which == 1 ? W1 : W2);
        bias = which == 0 ? b0 : (which == 1 ? b1 : b2);
    } else {
        which = 0; ncol0 = blockIdx.x * 128; W = W0; bias = b0;
    }

    // staging: lane covers (row = seg*8 + lane/8, chunk = lane&7),
    // global chunk swizzled by row&7 so LDS stays DMA-contiguous yet reads conflict-free
    const int srow = lane >> 3;
    const int scg  = (lane & 7) ^ srow;
    const unsigned short* Ag[4];
    const unsigned short* Wg[4];
    #pragma unroll
    for (int j = 0; j < 4; ++j) {
        const int row = (wave * 4 + j) * 8 + srow;
        Ag[j] = A + (m0 + row) * DMODEL + scg * 8;
        Wg[j] = W + (ncol0 + row) * DMODEL + scg * 8;
    }

    f32x4 acc[4][4] = {};
    const bool vswap = (MODE == 0) && (which == 2);   // C^T only for V
    for (int kk = 0; kk < DMODEL; kk += 64) {
        __syncthreads();
        #pragma unroll
        for (int j = 0; j < 4; ++j) {
            GLDS(Ag[j] + kk, &As[(wave * 4 + j) * 512]);
            GLDS(Wg[j] + kk, &Bs[(wave * 4 + j) * 512]);
        }
        __syncthreads();
        #pragma unroll
        for (int u = 0; u < 2; ++u) {
            bf16x8 af[4], bfx[4];
            const int cs = ((u * 4 + quad) ^ (r15 & 7)) * 8;
            #pragma unroll
            for (int t = 0; t < 4; ++t) {
                af[t]  = *(const bf16x8*)&As[(wr * 64 + t * 16 + r15) * 64 + cs];
                bfx[t] = *(const bf16x8*)&Bs[(wc * 64 + t * 16 + r15) * 64 + cs];
            }
            if (vswap) {
                #pragma unroll
                for (int mt = 0; mt < 4; ++mt)
                    #pragma unroll
                    for (int nt = 0; nt < 4; ++nt)
                        acc[mt][nt] = __builtin_amdgcn_mfma_f32_16x16x32_bf16(
                            bfx[nt], af[mt], acc[mt][nt], 0, 0, 0);
            } else {
                #pragma unroll
                for (int mt = 0; mt < 4; ++mt)
                    #pragma unroll
                    for (int nt = 0; nt < 4; ++nt)
                        acc[mt][nt] = __builtin_amdgcn_mfma_f32_16x16x32_bf16(
                            af[mt], bfx[nt], acc[mt][nt], 0, 0, 0);
            }
        }
    }

    // epilogue — lane-contiguous stores only
    #pragma unroll
    for (int mt = 0; mt < 4; ++mt) {
        #pragma unroll
        for (int nt = 0; nt < 4; ++nt) {
            if (MODE == 1) {
                // C: row = quad*4+r, col = r15 -> 16 lanes x 4 B = 64 B runs
                const int row0 = m0 + wr * 64 + mt * 16 + quad * 4;
                const int col  = ncol0 + wc * 64 + nt * 16 + r15;
                const float bb = bias[col];
                #pragma unroll
                for (int r = 0; r < 4; ++r)
                    ((float*)o0)[(size_t)(row0 + r) * DMODEL + col] = acc[mt][nt][r] + bb;
            } else if (which < 2) {
                // Q/K, C orientation: lanes = 16 consecutive d (32 B runs)
                const int row0 = m0 + wr * 64 + mt * 16 + quad * 4;    // l base
                const int col  = ncol0 + wc * 64 + nt * 16 + r15;      // h*64 + d
                float bb = bias[col];
                const int h = col >> 6, d = col & (DK - 1);
                unsigned short* ow = (unsigned short*)(which == 0 ? o0 : o1);
                #pragma unroll
                for (int r = 0; r < 4; ++r) {
                    const int row = row0 + r;
                    const int b = row >> 11, l = row & (SEQ - 1);
                    float v = acc[mt][nt][r] + bb;
                    if (which == 0) v *= 0.18033688011112042f;  // 0.125*log2(e)
                    ow[((size_t)(b * NHEADS + h) * SEQ + l) * DK + d] = f2bf(v);
                }
            } else {
                // V, C^T orientation: lanes = 16 consecutive l (32 B runs), regs = 4 d
                const int l   = m0 + wr * 64 + mt * 16 + r15;          // seq row
                const int d0  = ncol0 + wc * 64 + nt * 16 + quad * 4;  // h*64 + d base
                const float4 b4 = *(const float4*)&bias[d0];
                const int b = l >> 11, l2 = l & (SEQ - 1);
                const int h = d0 >> 6, dd = d0 & (DK - 1);
                const size_t base = (size_t)(b * NHEADS + h) * (SEQ * DK)
                                  + (size_t)(l2 >> 6) * (DK * 64) + (l2 & 63);
                _Float16* ow = (_Float16*)o2;
                #pragma unroll
                for (int r = 0; r < 4; ++r) {
                    const float v = acc[mt][nt][r] + ((const float*)&b4)[r];
                    ow[base + (size_t)(dd + r) * 64] = (_Float16)v;
                }
            }
        }
    }
}

// ---------------- Flash attention, LDS-staged K/V, register P ----------------
// Q (pre-scaled by 0.125*log2e), K: [BH, L, 64] bf16; Vm: blocked fp16 [BH, kblk, dv, 64];
// mbf: [B,L] float bias (0 / -1e30). Out: bf16 [B, L, DMODEL], col = h*64+dv.
// S^T accumulator C-layout (key=quad*4+r, query=r15) doubles as the B-fragment of
// mfma_f32_16x16x16f16 (k=quad*4+j, n=lane&15) -> PV computed as O^T = V^T * P^T
// with zero LDS round-trip for P.
__global__ __launch_bounds__(256, 4) void flash_attn(
        const unsigned short* __restrict__ Q,
        const unsigned short* __restrict__ Km,
        const unsigned short* __restrict__ Vm,
        const float* __restrict__ mbf,
        unsigned short* __restrict__ Oa) {
    __shared__ unsigned short Ks[64 * 64];        // 8 KB  [key][dk] swizzled
    __shared__ unsigned short Vs[64 * 64];        // 8 KB  fp16 [dv][key] swizzled
    const int lane = threadIdx.x & 63;
    const int wave = threadIdx.x >> 6;
    const int quad = lane >> 4;
    const int r15  = lane & 15;

    // XCD-aware remap: each XCD walks one head's 16 q-tiles before moving on
    const int id   = (blockIdx.y << 4) | blockIdx.x;   // gridDim.x == 16
    const int xcd  = id & 7;
    const int slot = id >> 3;                          // 0..127
    const int bh   = xcd + ((slot >> 4) << 3);         // 0..63
    const int qt   = slot & 15;
    const int b = bh >> 4, h = bh & (NHEADS - 1);
    const int q0 = qt * 128 + wave * 32;

    const unsigned short* Qb = Q  + (size_t)bh * SEQ * DK;
    const unsigned short* Kb = Km + (size_t)bh * SEQ * DK;
    const unsigned short* Vb = Vm + (size_t)bh * SEQ * DK;
    const float* mb = mbf + b * SEQ;

    const int srow = lane >> 3;
    const int soff = (srow * 64) + (((lane & 7) ^ srow) * 8);

    // Q fragments (B operand of S^T MFMA): 2 q-frags x 2 k-halves
    bf16x8 bq[2][2];
    #pragma unroll
    for (int qf = 0; qf < 2; ++qf)
        #pragma unroll
        for (int u = 0; u < 2; ++u)
            bq[qf][u] = *(const bf16x8*)(Qb + (q0 + qf * 16 + r15) * DK + u * 32 + quad * 8);

    float l_part[2] = {0.f, 0.f};
    f32x4 oacc[2][4] = {};

    for (int kb = 0; kb < SEQ; kb += 64) {
        __syncthreads();
        const unsigned short* Kg = Kb + kb * 64;   // 64 rows x 128 B, contiguous
        const unsigned short* Vg = Vb + kb * 64;   // blocked tile, contiguous
        #pragma unroll
        for (int j = 0; j < 2; ++j) {
            const int wseg = wave * 2 + j;
            GLDS(Kg + wseg * 512 + soff, &Ks[wseg * 512]);
            GLDS(Vg + wseg * 512 + soff, &Vs[wseg * 512]);
        }
        __syncthreads();

        f16x4 pfrag[4][2];
        #pragma unroll
        for (int t = 0; t < 4; ++t) {
            const bf16x8 ak0 = *(const bf16x8*)&Ks[(t * 16 + r15) * 64 + ((quad ^ (r15 & 7)) * 8)];
            const bf16x8 ak1 = *(const bf16x8*)&Ks[(t * 16 + r15) * 64 + (((4 + quad) ^ (r15 & 7)) * 8)];
            const float4 m4 = *(const float4*)(mb + kb + t * 16 + quad * 4);
            #pragma unroll
            for (int qf = 0; qf < 2; ++qf) {
                f32x4 z = {};
                z = __builtin_amdgcn_mfma_f32_16x16x32_bf16(ak0, bq[qf][0], z, 0, 0, 0);
                z = __builtin_amdgcn_mfma_f32_16x16x32_bf16(ak1, bq[qf][1], z, 0, 0, 0);
                // z = S^T (log2 domain): lane holds (key=t*16+quad*4+r, query=r15)
                const float p0 = EXP2F(z[0] + m4.x);
                const float p1 = EXP2F(z[1] + m4.y);
                const float p2 = EXP2F(z[2] + m4.z);
                const float p3 = EXP2F(z[3] + m4.w);
                l_part[qf] += (p0 + p1) + (p2 + p3);
                uint2 pw;
                pw.x = pack_f16(p0, p1);
                pw.y = pack_f16(p2, p3);
                pfrag[t][qf] = __builtin_bit_cast(f16x4, pw);
            }
        }

        // PV: O^T[dv][q] += V^T[dv][k] * P^T[k][q], 16x16x16 fp16 MFMA
        #pragma unroll
        for (int nt = 0; nt < 4; ++nt) {
            #pragma unroll
            for (int t = 0; t < 4; ++t) {
                // V^T A-frag: m=dv=nt*16+r15, k=key=t*16+quad*4.. (+3), swizzled chunk
                const int chunk = (2 * t + (quad >> 1)) ^ (r15 & 7);
                const f16x4 vf = *(const f16x4*)&Vs[(nt * 16 + r15) * 64 + chunk * 8 + (quad & 1) * 4];
                #pragma unroll
                for (int qf = 0; qf < 2; ++qf)
                    oacc[qf][nt] = __builtin_amdgcn_mfma_f32_16x16x16f16(
                        vf, pfrag[t][qf], oacc[qf][nt], 0, 0, 0);
            }
        }
    }

    #pragma unroll
    for (int qf = 0; qf < 2; ++qf) {
        float l = l_part[qf];
        l += __shfl_xor(l, 16);
        l += __shfl_xor(l, 32);                  // l for query r15 — already per-lane
        const float rl = __builtin_amdgcn_rcpf(l);
        const int row = q0 + qf * 16 + r15;      // query
        #pragma unroll
        for (int nt = 0; nt < 4; ++nt) {
            // O^T C-layout: lane holds dv = nt*16 + quad*4 + r, query = r15
            const int col0 = h * DK + nt * 16 + quad * 4;
            uint2 pw;
            pw.x = pack_bf16(oacc[qf][nt][0] * rl, oacc[qf][nt][1] * rl);
            pw.y = pack_bf16(oacc[qf][nt][2] * rl, oacc[qf][nt][3] * rl);
            *(uint2*)&Oa[((size_t)b * SEQ + row) * DMODEL + col0] = pw;
        }
    }
}

extern "C" void kernel_launch(void* const* d_in, const int* in_sizes, int n_in,
                              void* d_out, int out_size, void* d_ws, size_t ws_size,
                              hipStream_t stream) {
    (void)in_sizes; (void)n_in; (void)out_size; (void)ws_size;
    const float* x  = (const float*)d_in[0];
    const int* mask = (const int*)d_in[1];
    const float* Wq = (const float*)d_in[2];
    const float* bq = (const float*)d_in[3];
    const float* Wk = (const float*)d_in[4];
    const float* bk = (const float*)d_in[5];
    const float* Wv = (const float*)d_in[6];
    const float* bv = (const float*)d_in[7];
    const float* Wo = (const float*)d_in[8];
    const float* bo = (const float*)d_in[9];
    float* out = (float*)d_out;

    char* ws = (char*)d_ws;
    unsigned short* xb  = (unsigned short*)(ws);                                   // 8192x1024 bf16
    unsigned short* wqb = (unsigned short*)(ws + 16777216);                        // 1024x1024 bf16
    unsigned short* wkb = (unsigned short*)(ws + 16777216 + 1 * 2097152);
    unsigned short* wvb = (unsigned short*)(ws + 16777216 + 2 * 2097152);
    unsigned short* wob = (unsigned short*)(ws + 16777216 + 3 * 2097152);
    unsigned short* qb  = (unsigned short*)(ws + 16777216 + 4 * 2097152);          // [BH,L,64]
    unsigned short* kb  = qb  + (size_t)MROWS * DMODEL;                            // [BH,L,64]
    unsigned short* vtb = kb  + (size_t)MROWS * DMODEL;                            // blocked V fp16
    unsigned short* ab  = vtb + (size_t)MROWS * DMODEL;                            // [B,L,DMODEL]
    float*          mbf = (float*)(ab + (size_t)MROWS * DMODEL);                   // [B,L]

    cvt_kernel<<<dim3(MROWS * DMODEL / 4 / 256), 256, 0, stream>>>(x, xb, MROWS * DMODEL / 4);
    cvtw_kernel<<<dim3(DMODEL * DMODEL / 4 / 256, 4), 256, 0, stream>>>(
        Wq, Wk, Wv, Wo, wqb, wkb, wvb, wob);
    maskbias_kernel<<<dim3(BATCH * SEQ / 256), 256, 0, stream>>>(mask, mbf, BATCH * SEQ);

    // fused QKV: grid.x = 3 weights x 8 n-tiles
    gemm128<0><<<dim3(24, MROWS / 128), 256, 0, stream>>>(
        xb, wqb, wkb, wvb, bq, bk, bv, qb, kb, vtb);

    flash_attn<<<dim3(16, BATCH * NHEADS), 256, 0, stream>>>(qb, kb, vtb, mbf, ab);

    gemm128<1><<<dim3(8, MROWS / 128), 256, 0, stream>>>(
        ab, wob, nullptr, nullptr, bo, nullptr, nullptr, out, nullptr, nullptr);
}

// Round 7
// 325.314 us; speedup vs baseline: 1.2734x; 1.2432x over previous
//
#include <hip/hip_runtime.h>
#include <stdint.h>

#define DMODEL 1024
#define NHEADS 16
#define DK     64
#define BATCH  4
#define SEQ    2048
#define MROWS  (BATCH*SEQ)   // 8192

typedef __bf16   bf16x8 __attribute__((ext_vector_type(8)));
typedef float    f32x4  __attribute__((ext_vector_type(4)));
typedef _Float16 f16x4  __attribute__((ext_vector_type(4)));

#if defined(__has_builtin)
#if __has_builtin(__builtin_amdgcn_exp2f)
#define EXP2F(x) __builtin_amdgcn_exp2f(x)
#endif
#endif
#ifndef EXP2F
#define EXP2F(x) exp2f(x)
#endif

__device__ __forceinline__ unsigned short f2bf(float f) {
    unsigned int u = __builtin_bit_cast(unsigned int, f);
    u += 0x7fffu + ((u >> 16) & 1u);   // round-to-nearest-even
    return (unsigned short)(u >> 16);
}

// pack two f32 -> two bf16 (round-to-nearest) in one v_perm
__device__ __forceinline__ unsigned int pack_bf16(float a, float b) {
    unsigned int ua = __builtin_bit_cast(unsigned int, a) + 0x8000u;
    unsigned int ub = __builtin_bit_cast(unsigned int, b) + 0x8000u;
    return __builtin_amdgcn_perm(ub, ua, 0x07060302u);  // lo16=a.hi16, hi16=b.hi16
}
// pack two f32 -> two fp16 (RTZ), single instruction
__device__ __forceinline__ unsigned int pack_f16(float a, float b) {
    return __builtin_bit_cast(unsigned int, __builtin_amdgcn_cvt_pkrtz(a, b));
}

// async global->LDS, 16 B per lane, LDS dest = uniform base + lane*16
#define GLDS(gp, lp) __builtin_amdgcn_global_load_lds( \
    (const __attribute__((address_space(1))) unsigned int*)(gp), \
    (__attribute__((address_space(3))) unsigned int*)(lp), 16, 0, 0)

// ---------------- fp32 -> bf16 cast, 4 elems/thread ----------------
__global__ void cvt_kernel(const float* __restrict__ src,
                           unsigned short* __restrict__ dst, int n4) {
    int i = blockIdx.x * blockDim.x + threadIdx.x;
    if (i >= n4) return;
    const float4 v = reinterpret_cast<const float4*>(src)[i];
    uint2 o;
    o.x = pack_bf16(v.x, v.y);
    o.y = pack_bf16(v.z, v.w);
    reinterpret_cast<uint2*>(dst)[i] = o;
}

// 4 weight matrices (1024x1024 each) in one launch; blockIdx.y selects
__global__ void cvtw_kernel(const float* __restrict__ w0, const float* __restrict__ w1,
                            const float* __restrict__ w2, const float* __restrict__ w3,
                            unsigned short* __restrict__ d0, unsigned short* __restrict__ d1,
                            unsigned short* __restrict__ d2, unsigned short* __restrict__ d3) {
    const float* s; unsigned short* d;
    switch (blockIdx.y) {
        case 0:  s = w0; d = d0; break;
        case 1:  s = w1; d = d1; break;
        case 2:  s = w2; d = d2; break;
        default: s = w3; d = d3; break;
    }
    const int i = blockIdx.x * blockDim.x + threadIdx.x;
    const float4 v = reinterpret_cast<const float4*>(s)[i];
    uint2 o;
    o.x = pack_bf16(v.x, v.y);
    o.y = pack_bf16(v.z, v.w);
    reinterpret_cast<uint2*>(d)[i] = o;
}

// mask[B,L] int32 -> float bias (0 or -1e30)
__global__ void maskbias_kernel(const int* __restrict__ m, float* __restrict__ o, int n) {
    const int i = blockIdx.x * blockDim.x + threadIdx.x;
    if (i < n) o[i] = m[i] ? 0.f : -1e30f;
}

// ---------------- 128x128-tile GEMM, BK=64, LDS staged ----------------
// C[M,N] = A[M,1024] * W[N,1024]^T + bias
// Single MFMA path (no operand-swap branch in the K-loop).
// MODE 0 epilogue: each wave transposes its 64x64 quadrant through its private
// 8 KB slice of the (now idle) As/Bs LDS, then stores ONLY global_store_dwordx4
// (16 B/lane, 8 KB contiguous per wave) — no sub-dword global stores anywhere.
//   Q (scaled 0.125*log2e), K: bf16 -> [BH, L, 64]
//   V: fp16 -> blocked [BH, l>>6, dv, l&63]
// MODE 1: C orientation, fp32 row-major out [M, 1024] (dword stores, 64 B runs)
template<int MODE>
__global__ __launch_bounds__(256, 4) void gemm128(
        const unsigned short* __restrict__ A,
        const unsigned short* __restrict__ W0,
        const unsigned short* __restrict__ W1,
        const unsigned short* __restrict__ W2,
        const float* __restrict__ b0,
        const float* __restrict__ b1,
        const float* __restrict__ b2,
        void* __restrict__ o0, void* __restrict__ o1, void* __restrict__ o2) {
    __shared__ unsigned short As[128 * 64];   // 16 KB, rows of 64 bf16, chunk-swizzled
    __shared__ unsigned short Bs[128 * 64];   // 16 KB
    const int lane = threadIdx.x & 63;
    const int wave = threadIdx.x >> 6;
    const int quad = lane >> 4;
    const int r15  = lane & 15;
    const int wr = wave >> 1, wc = wave & 1;
    const int m0 = blockIdx.y * 128;

    int which, ncol0;
    const unsigned short* W;
    const float* bias;
    if (MODE == 0) {
        which = blockIdx.x >> 3;
        ncol0 = (blockIdx.x & 7) * 128;
        W    = which == 0 ? W0 : (which == 1 ? W1 : W2);
        bias = which == 0 ? b0 : (which == 1 ? b1 : b2);
    } else {
        which = 0; ncol0 = blockIdx.x * 128; W = W0; bias = b0;
    }

    // staging: lane covers (row = seg*8 + lane/8, chunk = lane&7),
    // global chunk swizzled by row&7 so LDS stays DMA-contiguous yet reads conflict-free
    const int srow = lane >> 3;
    const int scg  = (lane & 7) ^ srow;
    const unsigned short* Ag[4];
    const unsigned short* Wg[4];
    #pragma unroll
    for (int j = 0; j < 4; ++j) {
        const int row = (wave * 4 + j) * 8 + srow;
        Ag[j] = A + (m0 + row) * DMODEL + scg * 8;
        Wg[j] = W + (ncol0 + row) * DMODEL + scg * 8;
    }

    f32x4 acc[4][4] = {};
    for (int kk = 0; kk < DMODEL; kk += 64) {
        __syncthreads();
        #pragma unroll
        for (int j = 0; j < 4; ++j) {
            GLDS(Ag[j] + kk, &As[(wave * 4 + j) * 512]);
            GLDS(Wg[j] + kk, &Bs[(wave * 4 + j) * 512]);
        }
        __syncthreads();
        #pragma unroll
        for (int u = 0; u < 2; ++u) {
            bf16x8 af[4], bfx[4];
            const int cs = ((u * 4 + quad) ^ (r15 & 7)) * 8;
            #pragma unroll
            for (int t = 0; t < 4; ++t) {
                af[t]  = *(const bf16x8*)&As[(wr * 64 + t * 16 + r15) * 64 + cs];
                bfx[t] = *(const bf16x8*)&Bs[(wc * 64 + t * 16 + r15) * 64 + cs];
            }
            #pragma unroll
            for (int mt = 0; mt < 4; ++mt)
                #pragma unroll
                for (int nt = 0; nt < 4; ++nt)
                    acc[mt][nt] = __builtin_amdgcn_mfma_f32_16x16x32_bf16(
                        af[mt], bfx[nt], acc[mt][nt], 0, 0, 0);
        }
    }

    if (MODE == 1) {
        // fp32 out, C layout: col = r15-contiguous dword stores (64 B runs)
        #pragma unroll
        for (int mt = 0; mt < 4; ++mt) {
            #pragma unroll
            for (int nt = 0; nt < 4; ++nt) {
                const int row0 = m0 + wr * 64 + mt * 16 + quad * 4;
                const int col  = ncol0 + wc * 64 + nt * 16 + r15;
                const float bb = bias[col];
                #pragma unroll
                for (int r = 0; r < 4; ++r)
                    ((float*)o0)[(size_t)(row0 + r) * DMODEL + col] = acc[mt][nt][r] + bb;
            }
        }
        return;
    }

    // ---- MODE 0 epilogue: per-wave LDS transpose, then dwordx4 stores ----
    __syncthreads();   // all waves done reading As/Bs in the K-loop
    unsigned short* Ts = (wave < 2) ? &As[wave * 4096] : &Bs[(wave - 2) * 4096];
    char* const Tb = (char*)Ts;    // 8 KB private region: 64x64 elems, 16 B chunks
                                   // row-major rows of 128 B, chunk-swizzled by row&7

    const int b_idx = m0 >> 11;                 // batch
    const int h     = (ncol0 >> 6) + wc;        // head
    const int l0    = (m0 & (SEQ - 1)) + wr * 64;

    if (which == 2) {
        // V: LDS rows = d (64), cols = l (64) fp16; 4 consecutive l per lane -> b64
        #pragma unroll
        for (int nt = 0; nt < 4; ++nt) {
            const float bb = bias[ncol0 + wc * 64 + nt * 16 + r15];
            const int drow = nt * 16 + r15;
            #pragma unroll
            for (int mt = 0; mt < 4; ++mt) {
                const int sw = (mt * 2 + (quad >> 1)) ^ (r15 & 7);
                uint2 pw;
                pw.x = pack_f16(acc[mt][nt][0] + bb, acc[mt][nt][1] + bb);
                pw.y = pack_f16(acc[mt][nt][2] + bb, acc[mt][nt][3] + bb);
                *(uint2*)(Tb + drow * 128 + sw * 16 + (quad & 1) * 8) = pw;
            }
        }
        _Float16* gout = (_Float16*)o2
            + (size_t)(b_idx * NHEADS + h) * (SEQ * DK) + (size_t)(l0 >> 6) * (DK * 64);
        #pragma unroll
        for (int seg = 0; seg < 8; ++seg) {
            const uint4 vv = *(const uint4*)(Tb + seg * 1024
                + (lane >> 3) * 128 + (((lane & 7) ^ (lane >> 3)) * 16));
            *(uint4*)(gout + seg * 512 + lane * 8) = vv;
        }
    } else {
        // Q/K: LDS rows = l (64), cols = d (64) bf16; scalar b16 writes (2-way max)
        #pragma unroll
        for (int nt = 0; nt < 4; ++nt) {
            const float bb = bias[ncol0 + wc * 64 + nt * 16 + r15];
            const int dloc = nt * 16 + r15;
            const int chb  = dloc >> 3;
            const int dby  = (dloc & 7) * 2;
            #pragma unroll
            for (int mt = 0; mt < 4; ++mt) {
                #pragma unroll
                for (int r = 0; r < 4; ++r) {
                    const int lloc = mt * 16 + quad * 4 + r;
                    float v = acc[mt][nt][r] + bb;
                    if (which == 0) v *= 0.18033688011112042f;  // 0.125*log2(e)
                    const int sw = chb ^ (lloc & 7);
                    *(unsigned short*)(Tb + lloc * 128 + sw * 16 + dby) = f2bf(v);
                }
            }
        }
        unsigned short* ow = (unsigned short*)(which == 0 ? o0 : o1);
        unsigned short* gout = ow + ((size_t)(b_idx * NHEADS + h) * SEQ + l0) * DK;
        #pragma unroll
        for (int seg = 0; seg < 8; ++seg) {
            const uint4 vv = *(const uint4*)(Tb + seg * 1024
                + (lane >> 3) * 128 + (((lane & 7) ^ (lane >> 3)) * 16));
            *(uint4*)(gout + seg * 512 + lane * 8) = vv;
        }
    }
}

// ---------------- Flash attention, LDS-staged K/V, register P ----------------
// Q (pre-scaled by 0.125*log2e), K: [BH, L, 64] bf16; Vm: blocked fp16 [BH, kblk, dv, 64];
// mbf: [B,L] float bias (0 / -1e30). Out: bf16 [B, L, DMODEL], col = h*64+dv.
// S^T accumulator C-layout (key=quad*4+r, query=r15) doubles as the B-fragment of
// mfma_f32_16x16x16f16 (k=quad*4+j, n=lane&15) -> PV computed as O^T = V^T * P^T
// with zero LDS round-trip for P.
__global__ __launch_bounds__(256, 4) void flash_attn(
        const unsigned short* __restrict__ Q,
        const unsigned short* __restrict__ Km,
        const unsigned short* __restrict__ Vm,
        const float* __restrict__ mbf,
        unsigned short* __restrict__ Oa) {
    __shared__ unsigned short Ks[64 * 64];        // 8 KB  [key][dk] swizzled
    __shared__ unsigned short Vs[64 * 64];        // 8 KB  fp16 [dv][key] swizzled
    const int lane = threadIdx.x & 63;
    const int wave = threadIdx.x >> 6;
    const int quad = lane >> 4;
    const int r15  = lane & 15;

    // XCD-aware remap: each XCD walks one head's 16 q-tiles before moving on
    const int id   = (blockIdx.y << 4) | blockIdx.x;   // gridDim.x == 16
    const int xcd  = id & 7;
    const int slot = id >> 3;                          // 0..127
    const int bh   = xcd + ((slot >> 4) << 3);         // 0..63
    const int qt   = slot & 15;
    const int b = bh >> 4, h = bh & (NHEADS - 1);
    const int q0 = qt * 128 + wave * 32;

    const unsigned short* Qb = Q  + (size_t)bh * SEQ * DK;
    const unsigned short* Kb = Km + (size_t)bh * SEQ * DK;
    const unsigned short* Vb = Vm + (size_t)bh * SEQ * DK;
    const float* mb = mbf + b * SEQ;

    const int srow = lane >> 3;
    const int soff = (srow * 64) + (((lane & 7) ^ srow) * 8);

    // Q fragments (B operand of S^T MFMA): 2 q-frags x 2 k-halves
    bf16x8 bq[2][2];
    #pragma unroll
    for (int qf = 0; qf < 2; ++qf)
        #pragma unroll
        for (int u = 0; u < 2; ++u)
            bq[qf][u] = *(const bf16x8*)(Qb + (q0 + qf * 16 + r15) * DK + u * 32 + quad * 8);

    float l_part[2] = {0.f, 0.f};
    f32x4 oacc[2][4] = {};

    for (int kb = 0; kb < SEQ; kb += 64) {
        __syncthreads();
        const unsigned short* Kg = Kb + kb * 64;   // 64 rows x 128 B, contiguous
        const unsigned short* Vg = Vb + kb * 64;   // blocked tile, contiguous
        #pragma unroll
        for (int j = 0; j < 2; ++j) {
            const int wseg = wave * 2 + j;
            GLDS(Kg + wseg * 512 + soff, &Ks[wseg * 512]);
            GLDS(Vg + wseg * 512 + soff, &Vs[wseg * 512]);
        }
        __syncthreads();

        f16x4 pfrag[4][2];
        #pragma unroll
        for (int t = 0; t < 4; ++t) {
            const bf16x8 ak0 = *(const bf16x8*)&Ks[(t * 16 + r15) * 64 + ((quad ^ (r15 & 7)) * 8)];
            const bf16x8 ak1 = *(const bf16x8*)&Ks[(t * 16 + r15) * 64 + (((4 + quad) ^ (r15 & 7)) * 8)];
            const float4 m4 = *(const float4*)(mb + kb + t * 16 + quad * 4);
            #pragma unroll
            for (int qf = 0; qf < 2; ++qf) {
                f32x4 z = {};
                z = __builtin_amdgcn_mfma_f32_16x16x32_bf16(ak0, bq[qf][0], z, 0, 0, 0);
                z = __builtin_amdgcn_mfma_f32_16x16x32_bf16(ak1, bq[qf][1], z, 0, 0, 0);
                // z = S^T (log2 domain): lane holds (key=t*16+quad*4+r, query=r15)
                const float p0 = EXP2F(z[0] + m4.x);
                const float p1 = EXP2F(z[1] + m4.y);
                const float p2 = EXP2F(z[2] + m4.z);
                const float p3 = EXP2F(z[3] + m4.w);
                l_part[qf] += (p0 + p1) + (p2 + p3);
                uint2 pw;
                pw.x = pack_f16(p0, p1);
                pw.y = pack_f16(p2, p3);
                pfrag[t][qf] = __builtin_bit_cast(f16x4, pw);
            }
        }

        // PV: O^T[dv][q] += V^T[dv][k] * P^T[k][q], 16x16x16 fp16 MFMA
        #pragma unroll
        for (int nt = 0; nt < 4; ++nt) {
            #pragma unroll
            for (int t = 0; t < 4; ++t) {
                // V^T A-frag: m=dv=nt*16+r15, k=key=t*16+quad*4.. (+3), swizzled chunk
                const int chunk = (2 * t + (quad >> 1)) ^ (r15 & 7);
                const f16x4 vf = *(const f16x4*)&Vs[(nt * 16 + r15) * 64 + chunk * 8 + (quad & 1) * 4];
                #pragma unroll
                for (int qf = 0; qf < 2; ++qf)
                    oacc[qf][nt] = __builtin_amdgcn_mfma_f32_16x16x16f16(
                        vf, pfrag[t][qf], oacc[qf][nt], 0, 0, 0);
            }
        }
    }

    #pragma unroll
    for (int qf = 0; qf < 2; ++qf) {
        float l = l_part[qf];
        l += __shfl_xor(l, 16);
        l += __shfl_xor(l, 32);                  // l for query r15 — already per-lane
        const float rl = __builtin_amdgcn_rcpf(l);
        const int row = q0 + qf * 16 + r15;      // query
        #pragma unroll
        for (int nt = 0; nt < 4; ++nt) {
            // O^T C-layout: lane holds dv = nt*16 + quad*4 + r, query = r15
            const int col0 = h * DK + nt * 16 + quad * 4;
            uint2 pw;
            pw.x = pack_bf16(oacc[qf][nt][0] * rl, oacc[qf][nt][1] * rl);
            pw.y = pack_bf16(oacc[qf][nt][2] * rl, oacc[qf][nt][3] * rl);
            *(uint2*)&Oa[((size_t)b * SEQ + row) * DMODEL + col0] = pw;
        }
    }
}

extern "C" void kernel_launch(void* const* d_in, const int* in_sizes, int n_in,
                              void* d_out, int out_size, void* d_ws, size_t ws_size,
                              hipStream_t stream) {
    (void)in_sizes; (void)n_in; (void)out_size; (void)ws_size;
    const float* x  = (const float*)d_in[0];
    const int* mask = (const int*)d_in[1];
    const float* Wq = (const float*)d_in[2];
    const float* bq = (const float*)d_in[3];
    const float* Wk = (const float*)d_in[4];
    const float* bk = (const float*)d_in[5];
    const float* Wv = (const float*)d_in[6];
    const float* bv = (const float*)d_in[7];
    const float* Wo = (const float*)d_in[8];
    const float* bo = (const float*)d_in[9];
    float* out = (float*)d_out;

    char* ws = (char*)d_ws;
    unsigned short* xb  = (unsigned short*)(ws);                                   // 8192x1024 bf16
    unsigned short* wqb = (unsigned short*)(ws + 16777216);                        // 1024x1024 bf16
    unsigned short* wkb = (unsigned short*)(ws + 16777216 + 1 * 2097152);
    unsigned short* wvb = (unsigned short*)(ws + 16777216 + 2 * 2097152);
    unsigned short* wob = (unsigned short*)(ws + 16777216 + 3 * 2097152);
    unsigned short* qb  = (unsigned short*)(ws + 16777216 + 4 * 2097152);          // [BH,L,64]
    unsigned short* kb  = qb  + (size_t)MROWS * DMODEL;                            // [BH,L,64]
    unsigned short* vtb = kb  + (size_t)MROWS * DMODEL;                            // blocked V fp16
    unsigned short* ab  = vtb + (size_t)MROWS * DMODEL;                            // [B,L,DMODEL]
    float*          mbf = (float*)(ab + (size_t)MROWS * DMODEL);                   // [B,L]

    cvt_kernel<<<dim3(MROWS * DMODEL / 4 / 256), 256, 0, stream>>>(x, xb, MROWS * DMODEL / 4);
    cvtw_kernel<<<dim3(DMODEL * DMODEL / 4 / 256, 4), 256, 0, stream>>>(
        Wq, Wk, Wv, Wo, wqb, wkb, wvb, wob);
    maskbias_kernel<<<dim3(BATCH * SEQ / 256), 256, 0, stream>>>(mask, mbf, BATCH * SEQ);

    // fused QKV: grid.x = 3 weights x 8 n-tiles
    gemm128<0><<<dim3(24, MROWS / 128), 256, 0, stream>>>(
        xb, wqb, wkb, wvb, bq, bk, bv, qb, kb, vtb);

    flash_attn<<<dim3(16, BATCH * NHEADS), 256, 0, stream>>>(qb, kb, vtb, mbf, ab);

    gemm128<1><<<dim3(8, MROWS / 128), 256, 0, stream>>>(
        ab, wob, nullptr, nullptr, bo, nullptr, nullptr, out, nullptr, nullptr);
}